// Round 6
// baseline (503.817 us; speedup 1.0000x reference)
//
#include <hip/hip_runtime.h>

typedef unsigned short ushort_t;
typedef unsigned int uint_t;
typedef _Float16 f16;
typedef f16 f16x8 __attribute__((ext_vector_type(8)));
typedef float f32x4 __attribute__((ext_vector_type(4)));

#define B_   16
#define S_   128
#define T_   1024
#define M_   16
#define H_   1024
#define OUTW 3094
#define NSPAN (B_*S_)      /* 2048  */
#define NROW  (NSPAN*M_)   /* 32768 */

// ---------- ws layout (bytes) ----------
#define WS_CONT   0                       /* f16  [32768][1024]   67,108,864 B */
#define WS_DOCT   67108864                /* f16  [16][1024][1024] 33,554,432 B */
#define WS_W1T    100663296               /* f16  [1024][1024]     2,097,152 B */
#define WS_SCORES 102760448               /* f32  [32768]            131,072 B */

// clamp that also kills NaN (fmaxf/fminf return the non-NaN operand)
__device__ __forceinline__ float sane(float v) {
  return fminf(fmaxf(v, -60000.f), 60000.f);
}
__device__ __forceinline__ ushort_t f16bits(float f) {
  union { f16 h; ushort_t u; } c; c.h = (f16)f; return c.u;
}
__device__ __forceinline__ void load_lds16(const void* g, void* l) {
  __builtin_amdgcn_global_load_lds(
      (const __attribute__((address_space(1))) uint_t*)g,
      (__attribute__((address_space(3))) uint_t*)l, 16, 0, 0);
}

// ---------------------------------------------------------------------------
// Transpose + f32->f16 convert: in f32 [z][R][C] -> out f16 [z][C][R]
// ---------------------------------------------------------------------------
__global__ __launch_bounds__(256) void tconv(const float* __restrict__ in,
                                             ushort_t* __restrict__ out,
                                             int R, int C) {
  __shared__ uint_t tile[64][65];
  const int tid = threadIdx.x;
  const int c0 = blockIdx.x * 64, r0 = blockIdx.y * 64;
  const size_t mo = (size_t)blockIdx.z * R * C;
  const float* ip = in + mo;
  ushort_t* op = out + mo;
  const int tx = tid & 63, ty = tid >> 6;
#pragma unroll
  for (int p = 0; p < 16; ++p) {
    int r = p * 4 + ty;
    tile[r][tx] = (uint_t)f16bits(ip[(size_t)(r0 + r) * C + c0 + tx]);
  }
  __syncthreads();
  const int rr = (tid & 31) * 2, cc0 = tid >> 5;  // cc0 in 0..7
  uint_t* op32 = (uint_t*)op;
#pragma unroll
  for (int p = 0; p < 8; ++p) {
    int c = cc0 + p * 8;
    uint_t lo = tile[rr][c] & 0xffffu;
    uint_t hi = tile[rr + 1][c] & 0xffffu;
    op32[((size_t)(c0 + c) * R + r0 + rr) >> 1] = lo | (hi << 16);
  }
}

// ---------------------------------------------------------------------------
// GEMM1 (ROUND 6): 128x256 tile, 8 waves (512 thr), BK=32, proven 2-barrier
// sync and R0 swizzle family. ct tiles 8 -> 4: A (f32, heavy) logical reads
// halve (604->302 MB), B staging per FLOP halves, gload_lds calls/wave/K-step
// 6 -> 4 while MFMA stays 16. LDS 16KB A(f32) + 16KB B(f16) = 32KB.
// Grid 1152 = (8 xcd) x (4 ct) x (36 pgg); pg = pgg*8+xcd -> (rt,b);
// the 4 ct-siblings of one pg share A panel + docT_b on one XCD's L2.
// rows [start(128)|end(128)|cont(2048)] per batch; start/end -> d_out (f32),
// cont -> ws contF (f16).
// ---------------------------------------------------------------------------
__global__ __launch_bounds__(512) void gemm1(const float* __restrict__ startm,
                                             const float* __restrict__ endm,
                                             const float* __restrict__ contm,
                                             const ushort_t* __restrict__ docT,
                                             float* __restrict__ out,
                                             f16* __restrict__ contF) {
  __shared__ float As[128 * 32];      // f32 A tile, 16 KB, 8x16B chunks/row
  __shared__ ushort_t Bs[256 * 32];   // f16 B tile, 16 KB, 4x16B chunks/row
  const int tid = threadIdx.x;
  const uint_t pid = blockIdx.x;
  const int xcd = pid & 7;
  const int s_  = pid >> 3;            // 0..143
  const int ct  = s_ & 3;              // 0..3 (256-col tile)
  const int pg  = (s_ >> 2) * 8 + xcd; // 0..287
  const int rt  = pg >> 4;             // 0..17
  const int b   = pg & 15;

  const float* Ap;
  if (rt == 0)      Ap = startm + (size_t)b * S_ * T_;
  else if (rt == 1) Ap = endm + (size_t)b * S_ * T_;
  else              Ap = contm + (size_t)b * (S_ * M_ * T_) + (size_t)(rt - 2) * 128 * T_;
  const ushort_t* Bp = docT + (size_t)b * (H_ * T_) + (size_t)ct * 256 * T_;

  const int lane = tid & 63, w = tid >> 6;   // 8 waves
  const int wr = w >> 2;                     // 0..1 (64-row band)
  const int wc = w & 3;                      // 0..3 (64-col band)
  const int quad = lane >> 4, l16 = lane & 15;
  // staging source coords (chunk-swizzled, R0 formulas)
  const int arow = lane >> 3;                       // A: 8 rows/call
  const int acol = ((lane & 7) ^ arow) * 4;         // phys chunk = c ^ (row&7)
  const int brow = lane >> 2;                       // B: 16 rows/call
  const int bcol = ((lane & 3) ^ ((lane >> 3) & 3)) * 8;  // c ^ ((row>>1)&3)

  f32x4 acc[4][4];
#pragma unroll
  for (int i = 0; i < 4; ++i)
#pragma unroll
    for (int j = 0; j < 4; ++j) acc[i][j] = (f32x4){0.f, 0.f, 0.f, 0.f};

  for (int k0 = 0; k0 < T_; k0 += 32) {
#pragma unroll
    for (int i = 0; i < 2; ++i) {     // A: 2 calls x 8 rows (8 waves x 16 rows)
      const int rb = w * 16 + i * 8;
      load_lds16(Ap + (size_t)(rb + arow) * T_ + k0 + acol, &As[rb * 32]);
    }
#pragma unroll
    for (int i = 0; i < 2; ++i) {     // B: 2 calls x 16 rows (8 waves x 32 rows)
      const int rb = i * 128 + w * 16;
      load_lds16(Bp + (size_t)(rb + brow) * T_ + k0 + bcol, &Bs[rb * 32]);
    }
    __syncthreads();
    f16x8 af[4], bfr[4];
#pragma unroll
    for (int i = 0; i < 4; ++i) {
      const int row = wr * 64 + i * 16 + l16;
      const int sw = row & 7;
      f32x4 lo = *(const f32x4*)&As[row * 32 + (((quad * 2) ^ sw) * 4)];
      f32x4 hi = *(const f32x4*)&As[row * 32 + (((quad * 2 + 1) ^ sw) * 4)];
      f16x8 h;
#pragma unroll
      for (int k = 0; k < 4; ++k) { h[k] = (f16)lo[k]; h[k + 4] = (f16)hi[k]; }
      af[i] = h;
    }
#pragma unroll
    for (int j = 0; j < 4; ++j) {
      const int row = wc * 64 + j * 16 + l16;
      const int sw = (row >> 1) & 3;
      bfr[j] = *(const f16x8*)&Bs[row * 32 + ((quad ^ sw) * 8)];
    }
#pragma unroll
    for (int i = 0; i < 4; ++i)
#pragma unroll
      for (int j = 0; j < 4; ++j)
        acc[i][j] = __builtin_amdgcn_mfma_f32_16x16x32_f16(af[i], bfr[j], acc[i][j], 0, 0, 0);
    __syncthreads();
  }

  if (rt < 2) {
    float* op = out + (size_t)b * S_ * OUTW + (size_t)rt * 1024 + (size_t)ct * 256;
#pragma unroll
    for (int i = 0; i < 4; ++i)
#pragma unroll
      for (int j = 0; j < 4; ++j)
#pragma unroll
        for (int r = 0; r < 4; ++r) {
          int row = wr * 64 + i * 16 + quad * 4 + r;
          int col = wc * 64 + j * 16 + l16;
          op[(size_t)row * OUTW + col] = sane(acc[i][j][r]);
        }
  } else {
    f16* cp = contF + ((size_t)b * 2048 + (size_t)(rt - 2) * 128) * H_ + (size_t)ct * 256;
#pragma unroll
    for (int i = 0; i < 4; ++i)
#pragma unroll
      for (int j = 0; j < 4; ++j)
#pragma unroll
        for (int r = 0; r < 4; ++r) {
          int row = wr * 64 + i * 16 + quad * 4 + r;
          int col = wc * 64 + j * 16 + l16;
          cp[(size_t)row * H_ + col] = (f16)sane(acc[i][j][r]);
        }
  }
}

// ---------------------------------------------------------------------------
// GEMM2 (unchanged from R5, part of 488us best): 128x256 tile, 8 waves,
// BK=32, 2-barrier. Fused relu(+b1)*W2 row-reduce -> atomicAdd scores.
// ---------------------------------------------------------------------------
__global__ __launch_bounds__(512) void gemm2(const f16* __restrict__ contF,
                                             const f16* __restrict__ W1T,
                                             const float* __restrict__ b1,
                                             const float* __restrict__ W2,
                                             float* __restrict__ scores) {
  __shared__ f16 As[128 * 32];   // 8 KB
  __shared__ f16 Bs[256 * 32];   // 16 KB
  const int tid = threadIdx.x;
  const uint_t pid = blockIdx.x;
  const int xcd = pid & 7;
  const int s_  = pid >> 3;        // 0..127
  const int ct  = s_ & 3;          // 0..3   (col tile of 256)
  const int g   = s_ >> 2;         // 0..31
  const int rt  = g * 8 + xcd;     // 0..255 (row tile of 128)

  const f16* Ap = contF + (size_t)rt * 128 * H_;
  const f16* Bp = W1T + (size_t)ct * 256 * H_;

  const int lane = tid & 63, w = tid >> 6;   // 8 waves
  const int wr = w >> 2;                     // 0..1 (64-row band)
  const int wc = w & 3;                      // 0..3 (64-col band)
  const int quad = lane >> 4, l16 = lane & 15;
  const int srow = lane >> 2;                               // 0..15
  const int scol = ((lane & 3) ^ ((lane >> 3) & 3)) * 8;    // f16 offset

  f32x4 acc[4][4];
#pragma unroll
  for (int i = 0; i < 4; ++i)
#pragma unroll
    for (int j = 0; j < 4; ++j) acc[i][j] = (f32x4){0.f, 0.f, 0.f, 0.f};

  for (int k0 = 0; k0 < H_; k0 += 32) {
    // A: 1 call x 16 rows per wave (8 waves x 16 = 128 rows)
    {
      const int rb = w * 16;
      load_lds16(Ap + (size_t)(rb + srow) * H_ + k0 + scol, &As[rb * 32]);
    }
    // B: 2 calls x 16 rows per wave (8 waves x 2 x 16 = 256 rows)
#pragma unroll
    for (int i = 0; i < 2; ++i) {
      const int rb = i * 128 + w * 16;
      load_lds16(Bp + (size_t)(rb + srow) * H_ + k0 + scol, &Bs[rb * 32]);
    }
    __syncthreads();
    f16x8 af[4], bfr[4];
#pragma unroll
    for (int i = 0; i < 4; ++i) {
      const int row = wr * 64 + i * 16 + l16;
      const int sw = (row >> 1) & 3;
      af[i] = *(const f16x8*)&As[row * 32 + ((quad ^ sw) * 8)];
    }
#pragma unroll
    for (int j = 0; j < 4; ++j) {
      const int row = wc * 64 + j * 16 + l16;
      const int sw = (row >> 1) & 3;
      bfr[j] = *(const f16x8*)&Bs[row * 32 + ((quad ^ sw) * 8)];
    }
#pragma unroll
    for (int i = 0; i < 4; ++i)
#pragma unroll
      for (int j = 0; j < 4; ++j)
        acc[i][j] = __builtin_amdgcn_mfma_f32_16x16x32_f16(af[i], bfr[j], acc[i][j], 0, 0, 0);
    __syncthreads();
  }

  const int colbase = ct * 256 + wc * 64;
#pragma unroll
  for (int i = 0; i < 4; ++i) {
#pragma unroll
    for (int r = 0; r < 4; ++r) {
      float t = 0.f;
#pragma unroll
      for (int j = 0; j < 4; ++j) {
        int c = colbase + j * 16 + l16;
        float v = acc[i][j][r] + b1[c];
        v = fmaxf(v, 0.f);
        t = fmaf(v, W2[c], t);
      }
      t += __shfl_xor(t, 1);
      t += __shfl_xor(t, 2);
      t += __shfl_xor(t, 4);
      t += __shfl_xor(t, 8);
      if (l16 == 0) {
        int row = rt * 128 + wr * 64 + i * 16 + quad * 4 + r;
        atomicAdd(&scores[row], t);
      }
    }
  }
}

// ---------------------------------------------------------------------------
// finalize: mask + softmax over m, weighted sum over cont, ling + width emb
// grid 2048 (one span), 256 thr
// ---------------------------------------------------------------------------
__global__ __launch_bounds__(256) void finalize(const f16* __restrict__ contF,
                                                const float* __restrict__ scores,
                                                const float* __restrict__ ling,
                                                const float* __restrict__ b2,
                                                const float* __restrict__ wtab,
                                                const int* __restrict__ width,
                                                float* __restrict__ out) {
  const int n = blockIdx.x;
  const int tid = threadIdx.x;
  __shared__ float sc[16];
  if (tid < 16) {
    float raw = scores[n * 16 + tid] + b2[0];
    if (raw != raw) raw = 0.0f;            // NaN guard (diagnostic safety)
    int wv = width[n];
    int wm = wv > 1 ? wv : 1;
    float s = (tid < wm) ? raw : 0.0f;     // scores * masks
    if (s == 0.0f) s = -9e9f;              // where(scores != 0, scores, -9e9)
    sc[tid] = s;
  }
  __syncthreads();
  float mx = sc[0];
#pragma unroll
  for (int m = 1; m < 16; ++m) mx = fmaxf(mx, sc[m]);
  float e[16];
  float ssum = 0.f;
#pragma unroll
  for (int m = 0; m < 16; ++m) { e[m] = __expf(sc[m] - mx); ssum += e[m]; }
  const float inv = 1.0f / ssum;
  const f16* cp = contF + (size_t)n * (M_ * H_);
  float* op = out + (size_t)n * OUTW;
#pragma unroll
  for (int hh = 0; hh < 4; ++hh) {
    int h = tid + hh * 256;
    float a = 0.f;
#pragma unroll
    for (int m = 0; m < 16; ++m) a = fmaf(e[m], (float)cp[m * H_ + h], a);
    op[2048 + h] = sane(a * inv);
  }
  if (tid < 2) op[3072 + tid] = ling[n * 2 + tid];
  if (tid < 20) {
    int wv = width[n];
    int wcl = wv < 4 ? wv : 4;
    if (wcl < 0) wcl = 0;
    op[3074 + tid] = wtab[wcl * 20 + tid];
  }
}

// ---------------------------------------------------------------------------
extern "C" void kernel_launch(void* const* d_in, const int* in_sizes, int n_in,
                              void* d_out, int out_size, void* d_ws, size_t ws_size,
                              hipStream_t stream) {
  const float* doc    = (const float*)d_in[0];
  const float* startm = (const float*)d_in[1];
  const float* endm   = (const float*)d_in[2];
  const float* contm  = (const float*)d_in[3];
  const float* ling   = (const float*)d_in[4];
  const float* W1     = (const float*)d_in[5];
  const float* b1     = (const float*)d_in[6];
  const float* W2     = (const float*)d_in[7];
  const float* b2     = (const float*)d_in[8];
  const float* wtab   = (const float*)d_in[9];
  const int*   width  = (const int*)d_in[10];
  float* out = (float*)d_out;

  char* ws = (char*)d_ws;
  f16*      contF  = (f16*)(ws + WS_CONT);
  ushort_t* docT   = (ushort_t*)(ws + WS_DOCT);
  f16*      W1T    = (f16*)(ws + WS_W1T);
  float*    scores = (float*)(ws + WS_SCORES);

  hipMemsetAsync(scores, 0, NROW * sizeof(float), stream);
  tconv<<<dim3(16, 16, 16), 256, 0, stream>>>(doc, docT, 1024, 1024);
  tconv<<<dim3(16, 16, 1), 256, 0, stream>>>(W1, (ushort_t*)W1T, 1024, 1024);
  gemm1<<<dim3(1152, 1, 1), 512, 0, stream>>>(startm, endm, contm, docT, out, contF);
  gemm2<<<dim3(1024, 1, 1), 512, 0, stream>>>(contF, (const f16*)W1T, b1, W2, scores);
  finalize<<<dim3(NSPAN, 1, 1), 256, 0, stream>>>(contF, scores, ling, b2, wtab, width, out);
}

// Round 7
// 469.438 us; speedup vs baseline: 1.0732x; 1.0732x over previous
//
#include <hip/hip_runtime.h>

typedef unsigned short ushort_t;
typedef unsigned int uint_t;
typedef _Float16 f16;
typedef f16 f16x8 __attribute__((ext_vector_type(8)));
typedef float f32x4 __attribute__((ext_vector_type(4)));

#define B_   16
#define S_   128
#define T_   1024
#define M_   16
#define H_   1024
#define OUTW 3094
#define NSPAN (B_*S_)      /* 2048  */
#define NROW  (NSPAN*M_)   /* 32768 */

// ---------- ws layout (bytes) ----------
#define WS_CONT   0                       /* f16  [32768][1024]   67,108,864 B */
#define WS_DOCT   67108864                /* f16  [16][1024][1024] 33,554,432 B */
#define WS_W1T    100663296               /* f16  [1024][1024]     2,097,152 B */
#define WS_SCORES 102760448               /* f32  [32768]            131,072 B */
#define WS_A16    102891520               /* f16  [16][2304][1024] 75,497,472 B (optional) */
#define WS_NEED_A16 178388992ULL

// clamp that also kills NaN (fmaxf/fminf return the non-NaN operand)
__device__ __forceinline__ float sane(float v) {
  return fminf(fmaxf(v, -60000.f), 60000.f);
}
__device__ __forceinline__ ushort_t f16bits(float f) {
  union { f16 h; ushort_t u; } c; c.h = (f16)f; return c.u;
}
__device__ __forceinline__ void load_lds16(const void* g, void* l) {
  __builtin_amdgcn_global_load_lds(
      (const __attribute__((address_space(1))) uint_t*)g,
      (__attribute__((address_space(3))) uint_t*)l, 16, 0, 0);
}

// ---------------------------------------------------------------------------
// Transpose + f32->f16 convert: in f32 [z][R][C] -> out f16 [z][C][R]
// ---------------------------------------------------------------------------
__global__ __launch_bounds__(256) void tconv(const float* __restrict__ in,
                                             ushort_t* __restrict__ out,
                                             int R, int C) {
  __shared__ uint_t tile[64][65];
  const int tid = threadIdx.x;
  const int c0 = blockIdx.x * 64, r0 = blockIdx.y * 64;
  const size_t mo = (size_t)blockIdx.z * R * C;
  const float* ip = in + mo;
  ushort_t* op = out + mo;
  const int tx = tid & 63, ty = tid >> 6;
#pragma unroll
  for (int p = 0; p < 16; ++p) {
    int r = p * 4 + ty;
    tile[r][tx] = (uint_t)f16bits(ip[(size_t)(r0 + r) * C + c0 + tx]);
  }
  __syncthreads();
  const int rr = (tid & 31) * 2, cc0 = tid >> 5;  // cc0 in 0..7
  uint_t* op32 = (uint_t*)op;
#pragma unroll
  for (int p = 0; p < 8; ++p) {
    int c = cc0 + p * 8;
    uint_t lo = tile[rr][c] & 0xffffu;
    uint_t hi = tile[rr + 1][c] & 0xffffu;
    op32[((size_t)(c0 + c) * R + r0 + rr) >> 1] = lo | (hi << 16);
  }
}

// ---------------------------------------------------------------------------
// aconv: gather [start(128)|end(128)|cont(2048)] rows per batch, f32 -> f16,
// into A16 [16][2304][1024]. One block per row, 128 thr x 8 elems.
// ---------------------------------------------------------------------------
__global__ __launch_bounds__(128) void aconv(const float* __restrict__ startm,
                                             const float* __restrict__ endm,
                                             const float* __restrict__ contm,
                                             f16* __restrict__ A16) {
  const int r = blockIdx.x;        // 0..2303
  const int b = blockIdx.y;        // 0..15
  const int tid = threadIdx.x;     // 0..127
  const float* src;
  if (r < 128)      src = startm + ((size_t)b * S_ + r) * T_;
  else if (r < 256) src = endm + ((size_t)b * S_ + (r - 128)) * T_;
  else              src = contm + ((size_t)b * S_ * M_ + (r - 256)) * T_;
  const int i = tid * 8;
  f32x4 lo = *(const f32x4*)(src + i);
  f32x4 hi = *(const f32x4*)(src + i + 4);
  f16x8 h;
#pragma unroll
  for (int k = 0; k < 4; ++k) { h[k] = (f16)lo[k]; h[k + 4] = (f16)hi[k]; }
  *(f16x8*)(A16 + ((size_t)b * 2304 + r) * T_ + i) = h;
}

// ---------------------------------------------------------------------------
// GEMM1f (f16 A path, m97-exact structure): A16 rows x docT_b, 128x128 tile,
// 4 waves, BK=32, 2-barrier, both operands via global_load_lds with the
// proven chunk swizzle c ^ ((row>>1)&3). LDS 8KB + 8KB.
// Grid 2304 = (8 ct, 18 rt, 16 b), XCD-swizzled.
// ---------------------------------------------------------------------------
__global__ __launch_bounds__(256) void gemm1f(const f16* __restrict__ A16,
                                              const ushort_t* __restrict__ docT,
                                              float* __restrict__ out,
                                              f16* __restrict__ contF) {
  __shared__ f16 As[128 * 32];        // 8 KB
  __shared__ ushort_t Bs[128 * 32];   // 8 KB
  const int tid = threadIdx.x;
  const uint_t pid = blockIdx.x;
  const int xcd = pid & 7;
  const int s_  = pid >> 3;
  const int ct  = s_ & 7;
  const int pg  = (s_ >> 3) * 8 + xcd;   // 0..287
  const int rt  = pg >> 4;
  const int b   = pg & 15;

  const f16* Ap = A16 + ((size_t)b * 2304 + (size_t)rt * 128) * T_;
  const ushort_t* Bp = docT + (size_t)b * (H_ * T_) + (size_t)ct * 128 * T_;

  const int lane = tid & 63, w = tid >> 6;
  const int wr = w >> 1, wc = w & 1;
  const int quad = lane >> 4, l16 = lane & 15;
  // staging coords (16 rows per call, 4 lanes per row, chunk-swizzled)
  const int srow = lane >> 2;
  const int scol = ((lane & 3) ^ ((lane >> 3) & 3)) * 8;  // c ^ ((row>>1)&3)

  f32x4 acc[4][4];
#pragma unroll
  for (int i = 0; i < 4; ++i)
#pragma unroll
    for (int j = 0; j < 4; ++j) acc[i][j] = (f32x4){0.f, 0.f, 0.f, 0.f};

  for (int k0 = 0; k0 < T_; k0 += 32) {
#pragma unroll
    for (int i = 0; i < 2; ++i) {     // A: 2 calls x 16 rows
      const int rb = w * 32 + i * 16;
      load_lds16(Ap + (size_t)(rb + srow) * T_ + k0 + scol, &As[rb * 32]);
    }
#pragma unroll
    for (int i = 0; i < 2; ++i) {     // B: 2 calls x 16 rows
      const int rb = w * 32 + i * 16;
      load_lds16(Bp + (size_t)(rb + srow) * T_ + k0 + scol, &Bs[rb * 32]);
    }
    __syncthreads();
    f16x8 af[4], bfr[4];
#pragma unroll
    for (int i = 0; i < 4; ++i) {
      const int row = wr * 64 + i * 16 + l16;
      const int sw = (row >> 1) & 3;
      af[i] = *(const f16x8*)&As[row * 32 + ((quad ^ sw) * 8)];
    }
#pragma unroll
    for (int j = 0; j < 4; ++j) {
      const int row = wc * 64 + j * 16 + l16;
      const int sw = (row >> 1) & 3;
      bfr[j] = *(const f16x8*)&Bs[row * 32 + ((quad ^ sw) * 8)];
    }
#pragma unroll
    for (int i = 0; i < 4; ++i)
#pragma unroll
      for (int j = 0; j < 4; ++j)
        acc[i][j] = __builtin_amdgcn_mfma_f32_16x16x32_f16(af[i], bfr[j], acc[i][j], 0, 0, 0);
    __syncthreads();
  }

  if (rt < 2) {
    float* op = out + (size_t)b * S_ * OUTW + (size_t)rt * 1024 + (size_t)ct * 128;
#pragma unroll
    for (int i = 0; i < 4; ++i)
#pragma unroll
      for (int j = 0; j < 4; ++j)
#pragma unroll
        for (int r = 0; r < 4; ++r) {
          int row = wr * 64 + i * 16 + quad * 4 + r;
          int col = wc * 64 + j * 16 + l16;
          op[(size_t)row * OUTW + col] = sane(acc[i][j][r]);
        }
  } else {
    f16* cp = contF + ((size_t)b * 2048 + (size_t)(rt - 2) * 128) * H_ + (size_t)ct * 128;
#pragma unroll
    for (int i = 0; i < 4; ++i)
#pragma unroll
      for (int j = 0; j < 4; ++j)
#pragma unroll
        for (int r = 0; r < 4; ++r) {
          int row = wr * 64 + i * 16 + quad * 4 + r;
          int col = wc * 64 + j * 16 + l16;
          cp[(size_t)row * H_ + col] = (f16)sane(acc[i][j][r]);
        }
  }
}

// ---------------------------------------------------------------------------
// GEMM1 (R0 fallback, f32 A in-kernel cvt) — used only if ws lacks A16 room.
// ---------------------------------------------------------------------------
__global__ __launch_bounds__(256) void gemm1(const float* __restrict__ startm,
                                             const float* __restrict__ endm,
                                             const float* __restrict__ contm,
                                             const ushort_t* __restrict__ docT,
                                             float* __restrict__ out,
                                             f16* __restrict__ contF) {
  __shared__ float As[128 * 32];      // f32 A tile, 16 KB
  __shared__ ushort_t Bs[128 * 32];   // f16 B tile,  8 KB
  const int tid = threadIdx.x;
  const uint_t pid = blockIdx.x;
  const int xcd = pid & 7;
  const int s_  = pid >> 3;
  const int ct  = s_ & 7;
  const int pg  = (s_ >> 3) * 8 + xcd;   // 0..287
  const int rt  = pg >> 4;
  const int b   = pg & 15;

  const float* Ap;
  if (rt == 0)      Ap = startm + (size_t)b * S_ * T_;
  else if (rt == 1) Ap = endm + (size_t)b * S_ * T_;
  else              Ap = contm + (size_t)b * (S_ * M_ * T_) + (size_t)(rt - 2) * 128 * T_;
  const ushort_t* Bp = docT + (size_t)b * (H_ * T_) + (size_t)ct * 128 * T_;

  const int lane = tid & 63, w = tid >> 6;
  const int wr = w >> 1, wc = w & 1;
  const int quad = lane >> 4, l16 = lane & 15;
  const int arow = lane >> 3;
  const int acol = ((lane & 7) ^ arow) * 4;
  const int brow = lane >> 2;
  const int bcol = ((lane & 3) ^ ((lane >> 3) & 3)) * 8;

  f32x4 acc[4][4];
#pragma unroll
  for (int i = 0; i < 4; ++i)
#pragma unroll
    for (int j = 0; j < 4; ++j) acc[i][j] = (f32x4){0.f, 0.f, 0.f, 0.f};

  for (int k0 = 0; k0 < T_; k0 += 32) {
#pragma unroll
    for (int i = 0; i < 4; ++i) {
      const int rb = w * 32 + i * 8;
      load_lds16(Ap + (size_t)(rb + arow) * T_ + k0 + acol, &As[rb * 32]);
    }
#pragma unroll
    for (int i = 0; i < 2; ++i) {
      const int rb = w * 32 + i * 16;
      load_lds16(Bp + (size_t)(rb + brow) * T_ + k0 + bcol, &Bs[rb * 32]);
    }
    __syncthreads();
    f16x8 af[4], bfr[4];
#pragma unroll
    for (int i = 0; i < 4; ++i) {
      const int row = wr * 64 + i * 16 + l16;
      const int sw = row & 7;
      f32x4 lo = *(const f32x4*)&As[row * 32 + (((quad * 2) ^ sw) * 4)];
      f32x4 hi = *(const f32x4*)&As[row * 32 + (((quad * 2 + 1) ^ sw) * 4)];
      f16x8 h;
#pragma unroll
      for (int k = 0; k < 4; ++k) { h[k] = (f16)lo[k]; h[k + 4] = (f16)hi[k]; }
      af[i] = h;
    }
#pragma unroll
    for (int j = 0; j < 4; ++j) {
      const int row = wc * 64 + j * 16 + l16;
      const int sw = (row >> 1) & 3;
      bfr[j] = *(const f16x8*)&Bs[row * 32 + ((quad ^ sw) * 8)];
    }
#pragma unroll
    for (int i = 0; i < 4; ++i)
#pragma unroll
      for (int j = 0; j < 4; ++j)
        acc[i][j] = __builtin_amdgcn_mfma_f32_16x16x32_f16(af[i], bfr[j], acc[i][j], 0, 0, 0);
    __syncthreads();
  }

  if (rt < 2) {
    float* op = out + (size_t)b * S_ * OUTW + (size_t)rt * 1024 + (size_t)ct * 128;
#pragma unroll
    for (int i = 0; i < 4; ++i)
#pragma unroll
      for (int j = 0; j < 4; ++j)
#pragma unroll
        for (int r = 0; r < 4; ++r) {
          int row = wr * 64 + i * 16 + quad * 4 + r;
          int col = wc * 64 + j * 16 + l16;
          op[(size_t)row * OUTW + col] = sane(acc[i][j][r]);
        }
  } else {
    f16* cp = contF + ((size_t)b * 2048 + (size_t)(rt - 2) * 128) * H_ + (size_t)ct * 128;
#pragma unroll
    for (int i = 0; i < 4; ++i)
#pragma unroll
      for (int j = 0; j < 4; ++j)
#pragma unroll
        for (int r = 0; r < 4; ++r) {
          int row = wr * 64 + i * 16 + quad * 4 + r;
          int col = wc * 64 + j * 16 + l16;
          cp[(size_t)row * H_ + col] = (f16)sane(acc[i][j][r]);
        }
  }
}

// ---------------------------------------------------------------------------
// GEMM2 (unchanged from R5, part of 488us best): 128x256 tile, 8 waves,
// BK=32, 2-barrier. Fused relu(+b1)*W2 row-reduce -> atomicAdd scores.
// ---------------------------------------------------------------------------
__global__ __launch_bounds__(512) void gemm2(const f16* __restrict__ contF,
                                             const f16* __restrict__ W1T,
                                             const float* __restrict__ b1,
                                             const float* __restrict__ W2,
                                             float* __restrict__ scores) {
  __shared__ f16 As[128 * 32];   // 8 KB
  __shared__ f16 Bs[256 * 32];   // 16 KB
  const int tid = threadIdx.x;
  const uint_t pid = blockIdx.x;
  const int xcd = pid & 7;
  const int s_  = pid >> 3;        // 0..127
  const int ct  = s_ & 3;          // 0..3   (col tile of 256)
  const int g   = s_ >> 2;         // 0..31
  const int rt  = g * 8 + xcd;     // 0..255 (row tile of 128)

  const f16* Ap = contF + (size_t)rt * 128 * H_;
  const f16* Bp = W1T + (size_t)ct * 256 * H_;

  const int lane = tid & 63, w = tid >> 6;   // 8 waves
  const int wr = w >> 2;                     // 0..1 (64-row band)
  const int wc = w & 3;                      // 0..3 (64-col band)
  const int quad = lane >> 4, l16 = lane & 15;
  const int srow = lane >> 2;                               // 0..15
  const int scol = ((lane & 3) ^ ((lane >> 3) & 3)) * 8;    // f16 offset

  f32x4 acc[4][4];
#pragma unroll
  for (int i = 0; i < 4; ++i)
#pragma unroll
    for (int j = 0; j < 4; ++j) acc[i][j] = (f32x4){0.f, 0.f, 0.f, 0.f};

  for (int k0 = 0; k0 < H_; k0 += 32) {
    {
      const int rb = w * 16;
      load_lds16(Ap + (size_t)(rb + srow) * H_ + k0 + scol, &As[rb * 32]);
    }
#pragma unroll
    for (int i = 0; i < 2; ++i) {
      const int rb = i * 128 + w * 16;
      load_lds16(Bp + (size_t)(rb + srow) * H_ + k0 + scol, &Bs[rb * 32]);
    }
    __syncthreads();
    f16x8 af[4], bfr[4];
#pragma unroll
    for (int i = 0; i < 4; ++i) {
      const int row = wr * 64 + i * 16 + l16;
      const int sw = (row >> 1) & 3;
      af[i] = *(const f16x8*)&As[row * 32 + ((quad ^ sw) * 8)];
    }
#pragma unroll
    for (int j = 0; j < 4; ++j) {
      const int row = wc * 64 + j * 16 + l16;
      const int sw = (row >> 1) & 3;
      bfr[j] = *(const f16x8*)&Bs[row * 32 + ((quad ^ sw) * 8)];
    }
#pragma unroll
    for (int i = 0; i < 4; ++i)
#pragma unroll
      for (int j = 0; j < 4; ++j)
        acc[i][j] = __builtin_amdgcn_mfma_f32_16x16x32_f16(af[i], bfr[j], acc[i][j], 0, 0, 0);
    __syncthreads();
  }

  const int colbase = ct * 256 + wc * 64;
#pragma unroll
  for (int i = 0; i < 4; ++i) {
#pragma unroll
    for (int r = 0; r < 4; ++r) {
      float t = 0.f;
#pragma unroll
      for (int j = 0; j < 4; ++j) {
        int c = colbase + j * 16 + l16;
        float v = acc[i][j][r] + b1[c];
        v = fmaxf(v, 0.f);
        t = fmaf(v, W2[c], t);
      }
      t += __shfl_xor(t, 1);
      t += __shfl_xor(t, 2);
      t += __shfl_xor(t, 4);
      t += __shfl_xor(t, 8);
      if (l16 == 0) {
        int row = rt * 128 + wr * 64 + i * 16 + quad * 4 + r;
        atomicAdd(&scores[row], t);
      }
    }
  }
}

// ---------------------------------------------------------------------------
// finalize: mask + softmax over m, weighted sum over cont, ling + width emb
// grid 2048 (one span), 256 thr
// ---------------------------------------------------------------------------
__global__ __launch_bounds__(256) void finalize(const f16* __restrict__ contF,
                                                const float* __restrict__ scores,
                                                const float* __restrict__ ling,
                                                const float* __restrict__ b2,
                                                const float* __restrict__ wtab,
                                                const int* __restrict__ width,
                                                float* __restrict__ out) {
  const int n = blockIdx.x;
  const int tid = threadIdx.x;
  __shared__ float sc[16];
  if (tid < 16) {
    float raw = scores[n * 16 + tid] + b2[0];
    if (raw != raw) raw = 0.0f;            // NaN guard (diagnostic safety)
    int wv = width[n];
    int wm = wv > 1 ? wv : 1;
    float s = (tid < wm) ? raw : 0.0f;     // scores * masks
    if (s == 0.0f) s = -9e9f;              // where(scores != 0, scores, -9e9)
    sc[tid] = s;
  }
  __syncthreads();
  float mx = sc[0];
#pragma unroll
  for (int m = 1; m < 16; ++m) mx = fmaxf(mx, sc[m]);
  float e[16];
  float ssum = 0.f;
#pragma unroll
  for (int m = 0; m < 16; ++m) { e[m] = __expf(sc[m] - mx); ssum += e[m]; }
  const float inv = 1.0f / ssum;
  const f16* cp = contF + (size_t)n * (M_ * H_);
  float* op = out + (size_t)n * OUTW;
#pragma unroll
  for (int hh = 0; hh < 4; ++hh) {
    int h = tid + hh * 256;
    float a = 0.f;
#pragma unroll
    for (int m = 0; m < 16; ++m) a = fmaf(e[m], (float)cp[m * H_ + h], a);
    op[2048 + h] = sane(a * inv);
  }
  if (tid < 2) op[3072 + tid] = ling[n * 2 + tid];
  if (tid < 20) {
    int wv = width[n];
    int wcl = wv < 4 ? wv : 4;
    if (wcl < 0) wcl = 0;
    op[3074 + tid] = wtab[wcl * 20 + tid];
  }
}

// ---------------------------------------------------------------------------
extern "C" void kernel_launch(void* const* d_in, const int* in_sizes, int n_in,
                              void* d_out, int out_size, void* d_ws, size_t ws_size,
                              hipStream_t stream) {
  const float* doc    = (const float*)d_in[0];
  const float* startm = (const float*)d_in[1];
  const float* endm   = (const float*)d_in[2];
  const float* contm  = (const float*)d_in[3];
  const float* ling   = (const float*)d_in[4];
  const float* W1     = (const float*)d_in[5];
  const float* b1     = (const float*)d_in[6];
  const float* W2     = (const float*)d_in[7];
  const float* b2     = (const float*)d_in[8];
  const float* wtab   = (const float*)d_in[9];
  const int*   width  = (const int*)d_in[10];
  float* out = (float*)d_out;

  char* ws = (char*)d_ws;
  f16*      contF  = (f16*)(ws + WS_CONT);
  ushort_t* docT   = (ushort_t*)(ws + WS_DOCT);
  f16*      W1T    = (f16*)(ws + WS_W1T);
  float*    scores = (float*)(ws + WS_SCORES);
  f16*      A16    = (f16*)(ws + WS_A16);

  hipMemsetAsync(scores, 0, NROW * sizeof(float), stream);
  tconv<<<dim3(16, 16, 16), 256, 0, stream>>>(doc, docT, 1024, 1024);
  tconv<<<dim3(16, 16, 1), 256, 0, stream>>>(W1, (ushort_t*)W1T, 1024, 1024);
  if (ws_size >= WS_NEED_A16) {
    aconv<<<dim3(2304, 16, 1), 128, 0, stream>>>(startm, endm, contm, A16);
    gemm1f<<<dim3(2304, 1, 1), 256, 0, stream>>>(A16, docT, out, contF);
  } else {
    gemm1<<<dim3(2304, 1, 1), 256, 0, stream>>>(startm, endm, contm, docT, out, contF);
  }
  gemm2<<<dim3(1024, 1, 1), 512, 0, stream>>>(contF, (const f16*)W1T, b1, W2, scores);
  finalize<<<dim3(NSPAN, 1, 1), 256, 0, stream>>>(contF, scores, ling, b2, wtab, width, out);
}